// Round 7
// baseline (368.752 us; speedup 1.0000x reference)
//
#include <hip/hip_runtime.h>

#define NTOK 4096
#define HID 1024
#define QDIM 512
#define HEADS 4
#define NKEYS 128
#define TOPK 8
#define INTERDIM 4096

typedef __bf16 bf16x8 __attribute__((ext_vector_type(8)));
typedef __bf16 bf16x4 __attribute__((ext_vector_type(4)));
typedef float f32x4 __attribute__((ext_vector_type(4)));

__device__ __forceinline__ float siluf(float x) { return x / (1.f + __expf(-x)); }
__device__ __forceinline__ float dot4(float4 a, float4 b) {
  return a.x * b.x + a.y * b.y + a.z * b.z + a.w * b.w;
}
__device__ __forceinline__ unsigned sortable(float f) {
  unsigned u = __float_as_uint(f);
  return (u & 0x80000000u) ? ~u : (u | 0x80000000u);
}
__device__ __forceinline__ float bfl(unsigned u) { return __uint_as_float(u << 16); }
__device__ __forceinline__ float bfh(unsigned u) { return __uint_as_float(u & 0xFFFF0000u); }

#define GLD_LDS16(g, l)                                                                   \
  __builtin_amdgcn_global_load_lds(                                                      \
      (const __attribute__((address_space(1))) unsigned int*)(g),                        \
      (__attribute__((address_space(3))) unsigned int*)(l), 16, 0, 0)

// ---------------- fp32 -> bf16 cast ----------------
__global__ __launch_bounds__(256) void cast_bf16_kernel(const float* __restrict__ in,
                                                        __bf16* __restrict__ out, int n4)
{
  const int stride = gridDim.x * blockDim.x;
  for (int i = blockIdx.x * blockDim.x + threadIdx.x; i < n4; i += stride) {
    const float4 v = ((const float4*)in)[i];
    bf16x4 o;
    o[0] = (__bf16)v.x; o[1] = (__bf16)v.y; o[2] = (__bf16)v.z; o[3] = (__bf16)v.w;
    ((bf16x4*)out)[i] = o;
  }
}

// Wg/Wu -> interleaved Wgu [8192][1024] bf16: 16-col group g even=gate, odd=up.
__global__ __launch_bounds__(256) void cast_wgu_kernel(const float* __restrict__ Wg,
                                                       const float* __restrict__ Wu,
                                                       __bf16* __restrict__ Wgu)
{
  const int stride = gridDim.x * blockDim.x;
  const int total = 8192 * (HID / 4);
  for (int i = blockIdx.x * blockDim.x + threadIdx.x; i < total; i += stride) {
    const int n = i >> 8;            // output row (256 float4 per row)
    const int kq = i & 255;
    const int g = n >> 4, e = n & 15;
    const int srow = ((g >> 1) << 4) + e;
    const float* src = ((g & 1) ? Wu : Wg) + (size_t)srow * HID + kq * 4;
    const float4 v = *(const float4*)src;
    bf16x4 o;
    o[0] = (__bf16)v.x; o[1] = (__bf16)v.y; o[2] = (__bf16)v.z; o[3] = (__bf16)v.w;
    ((bf16x4*)(Wgu + (size_t)n * HID))[kq] = o;
  }
}

// keys [h][k][p][n] f32 -> kbf [(p*4+h)][k][n] bf16
__global__ __launch_bounds__(256) void cast_keys_kernel(const float* __restrict__ keys,
                                                        __bf16* __restrict__ kbf)
{
  const int i = blockIdx.x * 256 + threadIdx.x;
  const int n = i & 63, p = (i >> 6) & 1, k = (i >> 7) & 127, h = (i >> 14) & 3;
  kbf[(((size_t)(p * 4 + h) * NKEYS) + k) * 64 + n] = (__bf16)keys[i];
}

// ============ pipelined 256x256 gateup GEMM (8 waves, BK=32, 4-deep, swizzled) ============
// LDS tile layout: linear 256x32 bf16 with XOR swizzle on 128B row-pairs:
// flat byte L holds element (row = (L>>7)*2 + (bs>>6), colbyte = bs&63), bs = (L&127) ^ (((L>>7)&7)<<4).
// Staging writes linearly (gld_lds) from the inverse-swizzled GLOBAL address; reads apply the XOR.
__device__ __forceinline__ void stage_tile_swz(const __bf16* __restrict__ g, int ldk,
                                               __bf16* lds_wavebase, int tid)
{
#pragma unroll
  for (int rd = 0; rd < 2; ++rd) {
    const int cidx = rd * 512 + tid;
    const int vrow = cidx >> 3;
    const int bs = ((cidx & 7) ^ (vrow & 7)) << 4;
    const int srow = (vrow << 1) | (bs >> 6);
    const int scol = (bs & 63) >> 1;
    GLD_LDS16(g + (size_t)srow * ldk + scol, lds_wavebase + rd * 4096);
  }
}

__device__ __forceinline__ bf16x8 ldsfrag(const __bf16* tile, int r, int lhi)
{
  const int vrow = r >> 1;
  const int b = ((((r & 1) << 2) | lhi) ^ (vrow & 7)) << 4;
  return *(const bf16x8*)&tile[vrow * 64 + (b >> 1)];
}

__global__ __launch_bounds__(512, 2) void gemm_gateup(
    const __bf16* __restrict__ A,    // [M][K] hs_bf
    const __bf16* __restrict__ B,    // [8192][K] interleaved Wgu
    __bf16* __restrict__ Cb,         // [M][4096] inter
    int M, int N, int K)
{
  __shared__ __attribute__((aligned(16))) __bf16 Abuf[4][256 * 32];
  __shared__ __attribute__((aligned(16))) __bf16 Bbuf[4][256 * 32];

  const int nwg = gridDim.x * gridDim.y;
  int bid = blockIdx.y * gridDim.x + blockIdx.x;
  bid = (bid & 7) * (nwg >> 3) + (bid >> 3);          // XCD swizzle (nwg % 8 == 0)
  const int bx = bid % gridDim.x, by = bid / gridDim.x;
  const int m0 = by * 256, n0 = bx * 256;

  const int tid = threadIdx.x, wave = tid >> 6, lane = tid & 63;
  const int wr = wave >> 2, wc = wave & 3;            // 2 x 4 wave grid, wave tile 128x64
  const int lhi = lane >> 4, llo = lane & 15;

  const __bf16* Ag = A + (size_t)m0 * K;
  const __bf16* Bg = B + (size_t)n0 * K;

  f32x4 acc[8][4] = {};

  const int NT = K >> 5;  // 32
  // prologue: stage tiles 0..2 (12 loads/thread in flight)
#pragma unroll
  for (int t = 0; t < 3; ++t) {
    stage_tile_swz(Ag + t * 32, K, &Abuf[t][wave * 512], tid);
    stage_tile_swz(Bg + t * 32, K, &Bbuf[t][wave * 512], tid);
  }
  asm volatile("s_waitcnt vmcnt(8)" ::: "memory");    // tile 0 landed
  asm volatile("s_barrier" ::: "memory");

  for (int t = 0; t < NT; ++t) {
    if (t + 3 < NT) {  // stage t+3 into buf[(t+3)&3] (last read at t-1, barrier-separated)
      stage_tile_swz(Ag + (t + 3) * 32, K, &Abuf[(t + 3) & 3][wave * 512], tid);
      stage_tile_swz(Bg + (t + 3) * 32, K, &Bbuf[(t + 3) & 3][wave * 512], tid);
    }
    const __bf16* At = Abuf[t & 3];
    const __bf16* Bt = Bbuf[t & 3];
    bf16x8 afr[8], bfr[4];
#pragma unroll
    for (int mi = 0; mi < 8; ++mi) afr[mi] = ldsfrag(At, wr * 128 + mi * 16 + llo, lhi);
#pragma unroll
    for (int nj = 0; nj < 4; ++nj) bfr[nj] = ldsfrag(Bt, wc * 64 + nj * 16 + llo, lhi);
    __builtin_amdgcn_s_setprio(1);
#pragma unroll
    for (int mi = 0; mi < 8; ++mi)
#pragma unroll
      for (int nj = 0; nj < 4; ++nj)
        acc[mi][nj] = __builtin_amdgcn_mfma_f32_16x16x32_bf16(afr[mi], bfr[nj], acc[mi][nj], 0, 0, 0);
    __builtin_amdgcn_s_setprio(0);
    // counted vmcnt: retire exactly tile t+1's 4 loads; keep t+2/t+3 (8) in flight
    if (t + 3 < NT)      asm volatile("s_waitcnt vmcnt(8)" ::: "memory");
    else if (t + 2 < NT) asm volatile("s_waitcnt vmcnt(4)" ::: "memory");
    else if (t + 1 < NT) asm volatile("s_waitcnt vmcnt(0)" ::: "memory");
    asm volatile("s_barrier" ::: "memory");
  }

  // fused epilogue: fragment pair (2p, 2p+1) = (gate16, up16) of the same inter cols
  const int Nc = N >> 1;
#pragma unroll
  for (int mi = 0; mi < 8; ++mi)
#pragma unroll
    for (int p = 0; p < 2; ++p)
#pragma unroll
      for (int r = 0; r < 4; ++r) {
        const int row = m0 + wr * 128 + mi * 16 + lhi * 4 + r;
        const int icol = (n0 >> 1) + wc * 32 + p * 16 + llo;
        const float gv = acc[mi][2 * p][r];
        const float uv = acc[mi][2 * p + 1][r];
        Cb[(size_t)row * Nc + icol] = (__bf16)(siluf(gv) * uv);
      }
}

// ---------------- 2ph bf16 MFMA GEMM (q / down): C[M,N] = A[M,K] @ B[N,K]^T ----------------
template<bool OUT_BF16>
__global__ __launch_bounds__(512) void gemm_mfma(
    const __bf16* __restrict__ A, const __bf16* __restrict__ B0,
    void* __restrict__ Cv, int M, int N, int K)
{
  __shared__ __attribute__((aligned(16))) __bf16 As [128 * 32];
  __shared__ __attribute__((aligned(16))) __bf16 Bs0[128 * 32];

  const int nwg = gridDim.x * gridDim.y;
  int bid = blockIdx.y * gridDim.x + blockIdx.x;
  bid = (bid & 7) * (nwg >> 3) + (bid >> 3);
  const int bx = bid % gridDim.x, by = bid / gridDim.x;

  const int tid  = threadIdx.x;
  const int wave = tid >> 6;
  const int lane = tid & 63;
  const int m0 = by * 128;
  const int n0 = bx * 128;
  const int wr = wave >> 2, wc = wave & 3;
  const int lhi = lane >> 4, llo = lane & 15;

  f32x4 acc0[4][2] = {};

  const int r0 = tid >> 2, col0 = (tid & 3) * 8;
  __bf16* ldsA  = &As [(size_t)wave * 512];
  __bf16* ldsB0 = &Bs0[(size_t)wave * 512];

  for (int k0 = 0; k0 < K; k0 += 32) {
    GLD_LDS16(A  + (size_t)(m0 + r0) * K + k0 + col0, ldsA);
    GLD_LDS16(B0 + (size_t)(n0 + r0) * K + k0 + col0, ldsB0);
    __syncthreads();

    bf16x8 afr[4], bfr0[2];
#pragma unroll
    for (int mi = 0; mi < 4; ++mi)
      afr[mi] = *(const bf16x8*)&As[(wr * 64 + mi * 16 + llo) * 32 + lhi * 8];
#pragma unroll
    for (int nj = 0; nj < 2; ++nj)
      bfr0[nj] = *(const bf16x8*)&Bs0[(wc * 32 + nj * 16 + llo) * 32 + lhi * 8];
#pragma unroll
    for (int mi = 0; mi < 4; ++mi)
#pragma unroll
      for (int nj = 0; nj < 2; ++nj)
        acc0[mi][nj] = __builtin_amdgcn_mfma_f32_16x16x32_bf16(afr[mi], bfr0[nj], acc0[mi][nj], 0, 0, 0);
    __syncthreads();
  }

#pragma unroll
  for (int mi = 0; mi < 4; ++mi)
#pragma unroll
    for (int nj = 0; nj < 2; ++nj)
#pragma unroll
      for (int r = 0; r < 4; ++r) {
        const int row = m0 + wr * 64 + mi * 16 + lhi * 4 + r;
        const int col = n0 + wc * 32 + nj * 16 + llo;
        const float v = acc0[mi][nj][r];
        if constexpr (OUT_BF16) ((__bf16*)Cv)[(size_t)row * N + col] = (__bf16)v;
        else                    ((float*) Cv)[(size_t)row * N + col] = v;
      }
}

// ---------------- batched sims GEMM ----------------
__global__ __launch_bounds__(256) void sims_gemm(
    const __bf16* __restrict__ Qbf,  // [4096][512]
    const __bf16* __restrict__ Kbf,  // [8][128][64]
    float* __restrict__ S)           // [8][4096][128]
{
  __shared__ __attribute__((aligned(16))) __bf16 As[128 * 32];
  __shared__ __attribute__((aligned(16))) __bf16 Bs[128 * 32];

  const int z = blockIdx.y;
  const int p = z >> 2, h = z & 3;
  const __bf16* A = Qbf + p * 256 + h * 64;
  const __bf16* B = Kbf + (size_t)z * NKEYS * 64;
  float* C = S + (size_t)z * NTOK * NKEYS;

  const int tid  = threadIdx.x;
  const int wave = tid >> 6;
  const int lane = tid & 63;
  const int m0 = blockIdx.x * 128;
  const int wr = wave >> 1, wc = wave & 1;
  const int lhi = lane >> 4, llo = lane & 15;

  f32x4 acc[4][4] = {};

  const int c0 = tid, c1 = 256 + tid;
  const int r0 = c0 >> 2, col0 = (c0 & 3) * 8;
  const int r1 = c1 >> 2, col1 = (c1 & 3) * 8;
  __bf16* ldsA0 = &As[(wave * 64) * 8];
  __bf16* ldsA1 = &As[(256 + wave * 64) * 8];
  __bf16* ldsB0 = &Bs[(wave * 64) * 8];
  __bf16* ldsB1 = &Bs[(256 + wave * 64) * 8];

  for (int k0 = 0; k0 < 64; k0 += 32) {
    GLD_LDS16(A + (size_t)(m0 + r0) * 512 + k0 + col0, ldsA0);
    GLD_LDS16(A + (size_t)(m0 + r1) * 512 + k0 + col1, ldsA1);
    GLD_LDS16(B + (size_t)r0 * 64 + k0 + col0, ldsB0);
    GLD_LDS16(B + (size_t)r1 * 64 + k0 + col1, ldsB1);
    __syncthreads();

    bf16x8 afr[4], bfr[4];
#pragma unroll
    for (int mi = 0; mi < 4; ++mi)
      afr[mi] = *(const bf16x8*)&As[(wr * 64 + mi * 16 + llo) * 32 + lhi * 8];
#pragma unroll
    for (int nj = 0; nj < 4; ++nj)
      bfr[nj] = *(const bf16x8*)&Bs[(wc * 64 + nj * 16 + llo) * 32 + lhi * 8];
#pragma unroll
    for (int mi = 0; mi < 4; ++mi)
#pragma unroll
      for (int nj = 0; nj < 4; ++nj)
        acc[mi][nj] = __builtin_amdgcn_mfma_f32_16x16x32_bf16(afr[mi], bfr[nj], acc[mi][nj], 0, 0, 0);
    __syncthreads();
  }

#pragma unroll
  for (int mi = 0; mi < 4; ++mi)
#pragma unroll
    for (int nj = 0; nj < 4; ++nj)
#pragma unroll
      for (int r = 0; r < 4; ++r) {
        const int row = m0 + wr * 64 + mi * 16 + lhi * 4 + r;
        const int col = wc * 64 + nj * 16 + llo;
        C[(size_t)row * NKEYS + col] = acc[mi][nj][r];
      }
}

// ---------------- topk: 16 tokens x 1 head per block ----------------
__global__ __launch_bounds__(256) void topk_kernel(
    const float* __restrict__ S,
    int* __restrict__ out_idx,
    float* __restrict__ out_prob)
{
  const int g = blockIdx.x;
  const int h = blockIdx.y;
  const int t = threadIdx.x;
  const int tok0 = g * 16;

  __shared__ float    sims  [16][2][128];
  __shared__ unsigned packed[16][2][128];
  __shared__ unsigned cmax  [16][2][8];
  __shared__ int      cnt   [16][2];
  __shared__ unsigned char surv[16][2][128];
  __shared__ float    stv   [16][2][8];
  __shared__ unsigned char sti[16][2][8];
  __shared__ unsigned cnd   [16][64];

  const int ltok = t >> 4, j0 = (t & 15) * 8;
  unsigned pk[2][8];
#pragma unroll
  for (int p = 0; p < 2; ++p) {
    const float* src = S + (((size_t)(p * 4 + h) * NTOK) + tok0 + ltok) * NKEYS + j0;
    const float4 a = ((const float4*)src)[0];
    const float4 b = ((const float4*)src)[1];
    float v[8] = {a.x, a.y, a.z, a.w, b.x, b.y, b.z, b.w};
#pragma unroll
    for (int e = 0; e < 8; ++e) {
      const unsigned u = (sortable(v[e]) & 0xFFFFFF80u) | (unsigned)(127 - (j0 + e));
      sims  [ltok][p][j0 + e] = v[e];
      packed[ltok][p][j0 + e] = u;
      pk[p][e] = u;
    }
  }
  if (t < 32) cnt[t >> 1][t & 1] = 0;
  __syncthreads();

  {
    const int ctok = t >> 4, cp = (t >> 3) & 1, c = t & 7;
    const uint4* q = (const uint4*)&packed[ctok][cp][c * 16];
    unsigned m = 0;
#pragma unroll
    for (int r = 0; r < 4; ++r) {
      const uint4 u = q[r];
      m = max(m, max(max(u.x, u.y), max(u.z, u.w)));
    }
    cmax[ctok][cp][c] = m;
  }
  __syncthreads();

#pragma unroll
  for (int p = 0; p < 2; ++p) {
    const uint4* cm = (const uint4*)&cmax[ltok][p][0];
    const uint4 ca = cm[0], cb = cm[1];
    const unsigned t0 = min(min(min(ca.x, ca.y), min(ca.z, ca.w)),
                            min(min(cb.x, cb.y), min(cb.z, cb.w)));
#pragma unroll
    for (int e = 0; e < 8; ++e) {
      if (pk[p][e] >= t0) {
        const int s = atomicAdd(&cnt[ltok][p], 1);
        surv[ltok][p][s] = (unsigned char)(j0 + e);
      }
    }
  }
  __syncthreads();

  {
    const int gid = t >> 3, lane8 = t & 7;
    const int stok = gid >> 1, sp = gid & 1;
    const int n = cnt[stok][sp];
    const uint4* row = (const uint4*)&packed[stok][sp][0];
    for (int s = lane8; s < n; s += 8) {
      const int j = surv[stok][sp][s];
      const unsigned mypk = packed[stok][sp][j];
      int rk = 0;
#pragma unroll 8
      for (int q4 = 0; q4 < 32; ++q4) {
        const uint4 u = row[q4];
        rk += (u.x > mypk) + (u.y > mypk) + (u.z > mypk) + (u.w > mypk);
      }
      if (rk < TOPK) {
        stv[stok][sp][rk] = sims[stok][sp][j];
        sti[stok][sp][rk] = (unsigned char)j;
      }
    }
  }
  __syncthreads();

  const int w = t >> 6, l = t & 63;
  for (int round = 0; round < 4; ++round) {
    const int tok = w * 4 + round;
    const int ci = l >> 3, cj = l & 7;
    const float cv = stv[tok][0][ci] + stv[tok][1][cj];
    const unsigned cpk = (sortable(cv) & 0xFFFFFFC0u) | (unsigned)(63 - l);
    cnd[tok][l] = cpk;
    __syncthreads();
    int rk = 0;
    const uint4* row = (const uint4*)&cnd[tok][0];
#pragma unroll
    for (int q4 = 0; q4 < 16; ++q4) {
      const uint4 u = row[q4];
      rk += (u.x > cpk) + (u.y > cpk) + (u.z > cpk) + (u.w > cpk);
    }
    float mx = cv;
#pragma unroll
    for (int off = 32; off; off >>= 1) mx = fmaxf(mx, __shfl_xor(mx, off));
    const float e = (rk < TOPK) ? __expf(cv - mx) : 0.f;
    float sum = e;
#pragma unroll
    for (int off = 32; off; off >>= 1) sum += __shfl_xor(sum, off);
    if (rk < TOPK) {
      const int o = ((tok0 + tok) * HEADS + h) * TOPK + rk;
      out_idx [o] = (int)sti[tok][0][ci] * NKEYS + (int)sti[tok][1][cj];
      out_prob[o] = e / sum;
    }
  }
}

// ---------------- expert mixture (bf16 embeds): 4 waves x 8 experts ----------------
__global__ __launch_bounds__(256) void expert_kernel(
    const float* __restrict__ hs,
    const __bf16* __restrict__ down_e,
    const __bf16* __restrict__ up_e,
    const int* __restrict__ idx,
    const float* __restrict__ prob,
    float* __restrict__ out)
{
  const int token = blockIdx.x;
  const int t = threadIdx.x, w = t >> 6, l = t & 63;
  __shared__ float4 sred[4][256];

  const float4* hrow = (const float4*)(hs + (size_t)token * HID);
  const float4 h0 = hrow[2 * l], h1 = hrow[2 * l + 1];
  const float4 h2 = hrow[128 + 2 * l], h3 = hrow[128 + 2 * l + 1];
  float4 a0 = {0,0,0,0}, a1 = {0,0,0,0}, a2 = {0,0,0,0}, a3 = {0,0,0,0};

  const int*   tidx  = idx  + token * 32 + w * 8;
  const float* tprob = prob + token * 32 + w * 8;
#pragma unroll 2
  for (int e = 0; e < 8; ++e) {
    const int   ex = tidx[e];
    const float p  = tprob[e];
    const uint4* dr = (const uint4*)(down_e + (size_t)ex * HID);
    const uint4 dA = dr[l], dB = dr[64 + l];
    float part = h0.x * bfl(dA.x) + h0.y * bfh(dA.x) + h0.z * bfl(dA.y) + h0.w * bfh(dA.y)
               + h1.x * bfl(dA.z) + h1.y * bfh(dA.z) + h1.z * bfl(dA.w) + h1.w * bfh(dA.w)
               + h2.x * bfl(dB.x) + h2.y * bfh(dB.x) + h2.z * bfl(dB.y) + h2.w * bfh(dB.y)
               + h3.x * bfl(dB.z) + h3.y * bfh(dB.z) + h3.z * bfl(dB.w) + h3.w * bfh(dB.w);
#pragma unroll
    for (int off = 32; off; off >>= 1) part += __shfl_xor(part, off);
    const float wgt = siluf(part) * p;
    const uint4* ur = (const uint4*)(up_e + (size_t)ex * HID);
    const uint4 uA = ur[l], uB = ur[64 + l];
    a0.x += wgt * bfl(uA.x); a0.y += wgt * bfh(uA.x); a0.z += wgt * bfl(uA.y); a0.w += wgt * bfh(uA.y);
    a1.x += wgt * bfl(uA.z); a1.y += wgt * bfh(uA.z); a1.z += wgt * bfl(uA.w); a1.w += wgt * bfh(uA.w);
    a2.x += wgt * bfl(uB.x); a2.y += wgt * bfh(uB.x); a2.z += wgt * bfl(uB.y); a2.w += wgt * bfh(uB.y);
    a3.x += wgt * bfl(uB.z); a3.y += wgt * bfh(uB.z); a3.z += wgt * bfl(uB.w); a3.w += wgt * bfh(uB.w);
  }
  sred[w][2 * l] = a0; sred[w][2 * l + 1] = a1;
  sred[w][128 + 2 * l] = a2; sred[w][128 + 2 * l + 1] = a3;
  __syncthreads();

  const float4 r0 = sred[0][t], r1 = sred[1][t], r2 = sred[2][t], r3 = sred[3][t];
  float4* o = (float4*)(out + (size_t)token * HID);
  float4 cur = o[t];
  cur.x += r0.x + r1.x + r2.x + r3.x;
  cur.y += r0.y + r1.y + r2.y + r3.y;
  cur.z += r0.z + r1.z + r2.z + r3.z;
  cur.w += r0.w + r1.w + r2.w + r3.w;
  o[t] = cur;
}

extern "C" void kernel_launch(void* const* d_in, const int* in_sizes, int n_in,
                              void* d_out, int out_size, void* d_ws, size_t ws_size,
                              hipStream_t stream)
{
  const float* hs   = (const float*)d_in[0];
  const float* Wq   = (const float*)d_in[1];
  const float* keys = (const float*)d_in[2];
  const float* dwe  = (const float*)d_in[3];
  const float* upe  = (const float*)d_in[4];
  const float* Wg   = (const float*)d_in[5];
  const float* Wu   = (const float*)d_in[6];
  const float* Wd   = (const float*)d_in[7];
  float* out = (float*)d_out;

  __bf16* qbf     = (__bf16*)d_ws;                        // 4096*512 bf16 (4MB)
  __bf16* kbf     = qbf + (size_t)NTOK * QDIM;            // 8*128*64 bf16 (128KB)
  int*    idxb    = (int*)(kbf + 8 * NKEYS * 64);
  float*  probb   = (float*)(idxb + NTOK * HEADS * TOPK);
  __bf16* hs_bf   = (__bf16*)(probb + NTOK * HEADS * TOPK);
  __bf16* wq_bf   = hs_bf + (size_t)NTOK * HID;
  __bf16* wgu_bf  = wq_bf + (size_t)QDIM * HID;           // 8192*1024 bf16 (16MB)
  __bf16* wd_bf   = wgu_bf + (size_t)2 * INTERDIM * HID;
  __bf16* interbf = wd_bf + (size_t)HID * INTERDIM;       // 4096*4096 bf16 (32MB)
  float*  simsb   = (float*)interbf;                      // overlay, dead before gateup
  __bf16* dwe_bf  = interbf;                              // overlay, after down-GEMM
  __bf16* upe_bf  = hs_bf;                                // overlay (hs..wd span 33MB)

  cast_bf16_kernel<<<4096, 256, 0, stream>>>(hs, hs_bf, NTOK * HID / 4);
  cast_bf16_kernel<<<512,  256, 0, stream>>>(Wq, wq_bf, QDIM * HID / 4);
  cast_wgu_kernel<<<2048, 256, 0, stream>>>(Wg, Wu, wgu_bf);
  cast_bf16_kernel<<<4096, 256, 0, stream>>>(Wd, wd_bf, HID * INTERDIM / 4);
  cast_keys_kernel<<<256, 256, 0, stream>>>(keys, kbf);

  // q = hs @ Wq^T  (bf16 out)
  gemm_mfma<true><<<dim3(QDIM / 128, NTOK / 128), 512, 0, stream>>>(
      hs_bf, wq_bf, qbf, NTOK, QDIM, HID);

  // sims + topk
  sims_gemm<<<dim3(NTOK / 128, 8), 256, 0, stream>>>(qbf, kbf, simsb);
  topk_kernel<<<dim3(NTOK / 16, HEADS), 256, 0, stream>>>(simsb, idxb, probb);

  // inter = silu(hs @ Wg^T) * (hs @ Wu^T)  via concat-interleaved pipelined GEMM
  gemm_gateup<<<dim3(2 * INTERDIM / 256, NTOK / 256), 512, 0, stream>>>(
      hs_bf, wgu_bf, interbf, NTOK, 2 * INTERDIM, HID);

  // out = inter @ Wd^T  (f32 out)
  gemm_mfma<false><<<dim3(HID / 128, NTOK / 128), 512, 0, stream>>>(
      interbf, wd_bf, out, NTOK, HID, INTERDIM);

  // cast expert embeds into now-dead regions
  cast_bf16_kernel<<<4096, 256, 0, stream>>>(dwe, dwe_bf, 16384 * HID / 4);
  cast_bf16_kernel<<<4096, 256, 0, stream>>>(upe, upe_bf, 16384 * HID / 4);

  // out += expert mixture
  expert_kernel<<<NTOK, 256, 0, stream>>>(hs, dwe_bf, upe_bf, idxb, probb, out);
}

// Round 8
// 367.746 us; speedup vs baseline: 1.0027x; 1.0027x over previous
//
#include <hip/hip_runtime.h>

#define NTOK 4096
#define HID 1024
#define QDIM 512
#define HEADS 4
#define NKEYS 128
#define TOPK 8
#define INTERDIM 4096

typedef __bf16 bf16x8 __attribute__((ext_vector_type(8)));
typedef __bf16 bf16x4 __attribute__((ext_vector_type(4)));
typedef float f32x4 __attribute__((ext_vector_type(4)));

__device__ __forceinline__ float siluf(float x) { return x / (1.f + __expf(-x)); }
__device__ __forceinline__ float dot4(float4 a, float4 b) {
  return a.x * b.x + a.y * b.y + a.z * b.z + a.w * b.w;
}
__device__ __forceinline__ unsigned sortable(float f) {
  unsigned u = __float_as_uint(f);
  return (u & 0x80000000u) ? ~u : (u | 0x80000000u);
}
__device__ __forceinline__ float bfl(unsigned u) { return __uint_as_float(u << 16); }
__device__ __forceinline__ float bfh(unsigned u) { return __uint_as_float(u & 0xFFFF0000u); }

#define GLD_LDS16(g, l)                                                                   \
  __builtin_amdgcn_global_load_lds(                                                      \
      (const __attribute__((address_space(1))) unsigned int*)(g),                        \
      (__attribute__((address_space(3))) unsigned int*)(l), 16, 0, 0)

// ---------------- fp32 -> bf16 cast ----------------
__global__ __launch_bounds__(256) void cast_bf16_kernel(const float* __restrict__ in,
                                                        __bf16* __restrict__ out, int n4)
{
  const int stride = gridDim.x * blockDim.x;
  for (int i = blockIdx.x * blockDim.x + threadIdx.x; i < n4; i += stride) {
    const float4 v = ((const float4*)in)[i];
    bf16x4 o;
    o[0] = (__bf16)v.x; o[1] = (__bf16)v.y; o[2] = (__bf16)v.z; o[3] = (__bf16)v.w;
    ((bf16x4*)out)[i] = o;
  }
}

// Wg/Wu -> interleaved Wgu [8192][1024] bf16: 16-col group g even=gate, odd=up.
__global__ __launch_bounds__(256) void cast_wgu_kernel(const float* __restrict__ Wg,
                                                       const float* __restrict__ Wu,
                                                       __bf16* __restrict__ Wgu)
{
  const int stride = gridDim.x * blockDim.x;
  const int total = 8192 * (HID / 4);
  for (int i = blockIdx.x * blockDim.x + threadIdx.x; i < total; i += stride) {
    const int n = i >> 8;
    const int kq = i & 255;
    const int g = n >> 4, e = n & 15;
    const int srow = ((g >> 1) << 4) + e;
    const float* src = ((g & 1) ? Wu : Wg) + (size_t)srow * HID + kq * 4;
    const float4 v = *(const float4*)src;
    bf16x4 o;
    o[0] = (__bf16)v.x; o[1] = (__bf16)v.y; o[2] = (__bf16)v.z; o[3] = (__bf16)v.w;
    ((bf16x4*)(Wgu + (size_t)n * HID))[kq] = o;
  }
}

// keys [h][k][p][n] f32 -> kbf [(p*4+h)][k][n] bf16
__global__ __launch_bounds__(256) void cast_keys_kernel(const float* __restrict__ keys,
                                                        __bf16* __restrict__ kbf)
{
  const int i = blockIdx.x * 256 + threadIdx.x;
  const int n = i & 63, p = (i >> 6) & 1, k = (i >> 7) & 127, h = (i >> 14) & 3;
  kbf[(((size_t)(p * 4 + h) * NKEYS) + k) * 64 + n] = (__bf16)keys[i];
}

// ============ pipelined 256x256 gateup GEMM: 8 waves, BK=32, 4-deep, swizzled, 4-PHASE ====
// LDS + swizzle identical to the refcheck'd round-7 kernel (bank-conflict == 0).
__device__ __forceinline__ void stage_chunk_swz(const __bf16* __restrict__ g, int ldk,
                                                __bf16* lds_wavebase, int tid, int rd)
{
  const int cidx = rd * 512 + tid;
  const int vrow = cidx >> 3;
  const int bs = ((cidx & 7) ^ (vrow & 7)) << 4;
  const int srow = (vrow << 1) | (bs >> 6);
  const int scol = (bs & 63) >> 1;
  GLD_LDS16(g + (size_t)srow * ldk + scol, lds_wavebase + rd * 4096);
}

__device__ __forceinline__ bf16x8 ldsfrag(const __bf16* tile, int r, int lhi)
{
  const int vrow = r >> 1;
  const int b = ((((r & 1) << 2) | lhi) ^ (vrow & 7)) << 4;
  return *(const bf16x8*)&tile[vrow * 64 + (b >> 1)];
}

#define PHASE_BAR() do { asm volatile("s_barrier" ::: "memory"); \
                         __builtin_amdgcn_sched_barrier(0); } while (0)

__global__ __launch_bounds__(512, 2) void gemm_gateup(
    const __bf16* __restrict__ A,    // [M][K] hs_bf
    const __bf16* __restrict__ B,    // [8192][K] interleaved Wgu
    __bf16* __restrict__ Cb,         // [M][4096] inter
    int M, int N, int K)
{
  __shared__ __attribute__((aligned(16))) __bf16 Abuf[4][256 * 32];
  __shared__ __attribute__((aligned(16))) __bf16 Bbuf[4][256 * 32];

  const int nwg = gridDim.x * gridDim.y;
  int bid = blockIdx.y * gridDim.x + blockIdx.x;
  bid = (bid & 7) * (nwg >> 3) + (bid >> 3);          // XCD swizzle (nwg % 8 == 0)
  const int bx = bid % gridDim.x, by = bid / gridDim.x;
  const int m0 = by * 256, n0 = bx * 256;

  const int tid = threadIdx.x, wave = tid >> 6, lane = tid & 63;
  const int wr = wave >> 2, wc = wave & 3;            // 2 x 4 wave grid, wave tile 128x64
  const int lhi = lane >> 4, llo = lane & 15;

  const __bf16* Ag = A + (size_t)m0 * K;
  const __bf16* Bg = B + (size_t)n0 * K;

  f32x4 acc[8][4] = {};

  const int NT = K >> 5;  // 32
  // prologue: stage tiles 0..2 (12 loads/thread in flight)
#pragma unroll
  for (int t = 0; t < 3; ++t) {
    stage_chunk_swz(Ag + t * 32, K, &Abuf[t][wave * 512], tid, 0);
    stage_chunk_swz(Ag + t * 32, K, &Abuf[t][wave * 512], tid, 1);
    stage_chunk_swz(Bg + t * 32, K, &Bbuf[t][wave * 512], tid, 0);
    stage_chunk_swz(Bg + t * 32, K, &Bbuf[t][wave * 512], tid, 1);
  }
  asm volatile("s_waitcnt vmcnt(8)" ::: "memory");    // tile 0 landed
  asm volatile("s_barrier" ::: "memory");

  for (int t = 0; t < NT; ++t) {
    const bool pf = (t + 3 < NT);
    const __bf16* At = Abuf[t & 3];
    const __bf16* Bt = Bbuf[t & 3];
    __bf16* Ad = &Abuf[(t + 3) & 3][wave * 512];
    __bf16* Bd = &Bbuf[(t + 3) & 3][wave * 512];
    const __bf16* Ags = Ag + (t + 3) * 32;
    const __bf16* Bgs = Bg + (t + 3) * 32;
    bf16x8 afr[8], bfr[4];

    // ---- phase 0: read afr0-3 + bfr0-1, stage A-chunk0(t+3), MFMA quadrant (mi0-3, nj0-1)
#pragma unroll
    for (int mi = 0; mi < 4; ++mi) afr[mi] = ldsfrag(At, wr * 128 + mi * 16 + llo, lhi);
    bfr[0] = ldsfrag(Bt, wc * 64 + 0 * 16 + llo, lhi);
    bfr[1] = ldsfrag(Bt, wc * 64 + 1 * 16 + llo, lhi);
    if (pf) stage_chunk_swz(Ags, K, Ad, tid, 0);
    PHASE_BAR();
    __builtin_amdgcn_s_setprio(1);
#pragma unroll
    for (int mi = 0; mi < 4; ++mi)
#pragma unroll
      for (int nj = 0; nj < 2; ++nj)
        acc[mi][nj] = __builtin_amdgcn_mfma_f32_16x16x32_bf16(afr[mi], bfr[nj], acc[mi][nj], 0, 0, 0);
    __builtin_amdgcn_s_setprio(0);
    PHASE_BAR();

    // ---- phase 1: read bfr2-3, stage A-chunk1, MFMA (mi0-3, nj2-3)
    bfr[2] = ldsfrag(Bt, wc * 64 + 2 * 16 + llo, lhi);
    bfr[3] = ldsfrag(Bt, wc * 64 + 3 * 16 + llo, lhi);
    if (pf) stage_chunk_swz(Ags, K, Ad, tid, 1);
    PHASE_BAR();
    __builtin_amdgcn_s_setprio(1);
#pragma unroll
    for (int mi = 0; mi < 4; ++mi)
#pragma unroll
      for (int nj = 2; nj < 4; ++nj)
        acc[mi][nj] = __builtin_amdgcn_mfma_f32_16x16x32_bf16(afr[mi], bfr[nj], acc[mi][nj], 0, 0, 0);
    __builtin_amdgcn_s_setprio(0);
    PHASE_BAR();

    // ---- phase 2: read afr4-7, stage B-chunk0, MFMA (mi4-7, nj0-1)
#pragma unroll
    for (int mi = 4; mi < 8; ++mi) afr[mi] = ldsfrag(At, wr * 128 + mi * 16 + llo, lhi);
    if (pf) stage_chunk_swz(Bgs, K, Bd, tid, 0);
    PHASE_BAR();
    __builtin_amdgcn_s_setprio(1);
#pragma unroll
    for (int mi = 4; mi < 8; ++mi)
#pragma unroll
      for (int nj = 0; nj < 2; ++nj)
        acc[mi][nj] = __builtin_amdgcn_mfma_f32_16x16x32_bf16(afr[mi], bfr[nj], acc[mi][nj], 0, 0, 0);
    __builtin_amdgcn_s_setprio(0);
    PHASE_BAR();

    // ---- phase 3: stage B-chunk1, MFMA (mi4-7, nj2-3), tile-boundary vmcnt ladder
    if (pf) stage_chunk_swz(Bgs, K, Bd, tid, 1);
    PHASE_BAR();
    __builtin_amdgcn_s_setprio(1);
#pragma unroll
    for (int mi = 4; mi < 8; ++mi)
#pragma unroll
      for (int nj = 2; nj < 4; ++nj)
        acc[mi][nj] = __builtin_amdgcn_mfma_f32_16x16x32_bf16(afr[mi], bfr[nj], acc[mi][nj], 0, 0, 0);
    __builtin_amdgcn_s_setprio(0);
    __builtin_amdgcn_sched_barrier(0);
    // counted vmcnt: retire exactly tile t+1's 4 loads; keep t+2/t+3 (8) in flight
    if (pf)              asm volatile("s_waitcnt vmcnt(8)" ::: "memory");
    else if (t + 2 < NT) asm volatile("s_waitcnt vmcnt(4)" ::: "memory");
    else if (t + 1 < NT) asm volatile("s_waitcnt vmcnt(0)" ::: "memory");
    asm volatile("s_barrier" ::: "memory");
  }

  // fused epilogue: fragment pair (2p, 2p+1) = (gate16, up16) of the same inter cols
  const int Nc = N >> 1;
#pragma unroll
  for (int mi = 0; mi < 8; ++mi)
#pragma unroll
    for (int p = 0; p < 2; ++p)
#pragma unroll
      for (int r = 0; r < 4; ++r) {
        const int row = m0 + wr * 128 + mi * 16 + lhi * 4 + r;
        const int icol = (n0 >> 1) + wc * 32 + p * 16 + llo;
        const float gv = acc[mi][2 * p][r];
        const float uv = acc[mi][2 * p + 1][r];
        Cb[(size_t)row * Nc + icol] = (__bf16)(siluf(gv) * uv);
      }
}

// ---------------- 2ph bf16 MFMA GEMM (q / down): C[M,N] = A[M,K] @ B[N,K]^T ----------------
template<bool OUT_BF16>
__global__ __launch_bounds__(512) void gemm_mfma(
    const __bf16* __restrict__ A, const __bf16* __restrict__ B0,
    void* __restrict__ Cv, int M, int N, int K)
{
  __shared__ __attribute__((aligned(16))) __bf16 As [128 * 32];
  __shared__ __attribute__((aligned(16))) __bf16 Bs0[128 * 32];

  const int nwg = gridDim.x * gridDim.y;
  int bid = blockIdx.y * gridDim.x + blockIdx.x;
  bid = (bid & 7) * (nwg >> 3) + (bid >> 3);
  const int bx = bid % gridDim.x, by = bid / gridDim.x;

  const int tid  = threadIdx.x;
  const int wave = tid >> 6;
  const int lane = tid & 63;
  const int m0 = by * 128;
  const int n0 = bx * 128;
  const int wr = wave >> 2, wc = wave & 3;
  const int lhi = lane >> 4, llo = lane & 15;

  f32x4 acc0[4][2] = {};

  const int r0 = tid >> 2, col0 = (tid & 3) * 8;
  __bf16* ldsA  = &As [(size_t)wave * 512];
  __bf16* ldsB0 = &Bs0[(size_t)wave * 512];

  for (int k0 = 0; k0 < K; k0 += 32) {
    GLD_LDS16(A  + (size_t)(m0 + r0) * K + k0 + col0, ldsA);
    GLD_LDS16(B0 + (size_t)(n0 + r0) * K + k0 + col0, ldsB0);
    __syncthreads();

    bf16x8 afr[4], bfr0[2];
#pragma unroll
    for (int mi = 0; mi < 4; ++mi)
      afr[mi] = *(const bf16x8*)&As[(wr * 64 + mi * 16 + llo) * 32 + lhi * 8];
#pragma unroll
    for (int nj = 0; nj < 2; ++nj)
      bfr0[nj] = *(const bf16x8*)&Bs0[(wc * 32 + nj * 16 + llo) * 32 + lhi * 8];
#pragma unroll
    for (int mi = 0; mi < 4; ++mi)
#pragma unroll
      for (int nj = 0; nj < 2; ++nj)
        acc0[mi][nj] = __builtin_amdgcn_mfma_f32_16x16x32_bf16(afr[mi], bfr0[nj], acc0[mi][nj], 0, 0, 0);
    __syncthreads();
  }

#pragma unroll
  for (int mi = 0; mi < 4; ++mi)
#pragma unroll
    for (int nj = 0; nj < 2; ++nj)
#pragma unroll
      for (int r = 0; r < 4; ++r) {
        const int row = m0 + wr * 64 + mi * 16 + lhi * 4 + r;
        const int col = n0 + wc * 32 + nj * 16 + llo;
        const float v = acc0[mi][nj][r];
        if constexpr (OUT_BF16) ((__bf16*)Cv)[(size_t)row * N + col] = (__bf16)v;
        else                    ((float*) Cv)[(size_t)row * N + col] = v;
      }
}

// ---------------- batched sims GEMM ----------------
__global__ __launch_bounds__(256) void sims_gemm(
    const __bf16* __restrict__ Qbf,  // [4096][512]
    const __bf16* __restrict__ Kbf,  // [8][128][64]
    float* __restrict__ S)           // [8][4096][128]
{
  __shared__ __attribute__((aligned(16))) __bf16 As[128 * 32];
  __shared__ __attribute__((aligned(16))) __bf16 Bs[128 * 32];

  const int z = blockIdx.y;
  const int p = z >> 2, h = z & 3;
  const __bf16* A = Qbf + p * 256 + h * 64;
  const __bf16* B = Kbf + (size_t)z * NKEYS * 64;
  float* C = S + (size_t)z * NTOK * NKEYS;

  const int tid  = threadIdx.x;
  const int wave = tid >> 6;
  const int lane = tid & 63;
  const int m0 = blockIdx.x * 128;
  const int wr = wave >> 1, wc = wave & 1;
  const int lhi = lane >> 4, llo = lane & 15;

  f32x4 acc[4][4] = {};

  const int c0 = tid, c1 = 256 + tid;
  const int r0 = c0 >> 2, col0 = (c0 & 3) * 8;
  const int r1 = c1 >> 2, col1 = (c1 & 3) * 8;
  __bf16* ldsA0 = &As[(wave * 64) * 8];
  __bf16* ldsA1 = &As[(256 + wave * 64) * 8];
  __bf16* ldsB0 = &Bs[(wave * 64) * 8];
  __bf16* ldsB1 = &Bs[(256 + wave * 64) * 8];

  for (int k0 = 0; k0 < 64; k0 += 32) {
    GLD_LDS16(A + (size_t)(m0 + r0) * 512 + k0 + col0, ldsA0);
    GLD_LDS16(A + (size_t)(m0 + r1) * 512 + k0 + col1, ldsA1);
    GLD_LDS16(B + (size_t)r0 * 64 + k0 + col0, ldsB0);
    GLD_LDS16(B + (size_t)r1 * 64 + k0 + col1, ldsB1);
    __syncthreads();

    bf16x8 afr[4], bfr[4];
#pragma unroll
    for (int mi = 0; mi < 4; ++mi)
      afr[mi] = *(const bf16x8*)&As[(wr * 64 + mi * 16 + llo) * 32 + lhi * 8];
#pragma unroll
    for (int nj = 0; nj < 4; ++nj)
      bfr[nj] = *(const bf16x8*)&Bs[(wc * 64 + nj * 16 + llo) * 32 + lhi * 8];
#pragma unroll
    for (int mi = 0; mi < 4; ++mi)
#pragma unroll
      for (int nj = 0; nj < 4; ++nj)
        acc[mi][nj] = __builtin_amdgcn_mfma_f32_16x16x32_bf16(afr[mi], bfr[nj], acc[mi][nj], 0, 0, 0);
    __syncthreads();
  }

#pragma unroll
  for (int mi = 0; mi < 4; ++mi)
#pragma unroll
    for (int nj = 0; nj < 4; ++nj)
#pragma unroll
      for (int r = 0; r < 4; ++r) {
        const int row = m0 + wr * 64 + mi * 16 + lhi * 4 + r;
        const int col = wc * 64 + nj * 16 + llo;
        C[(size_t)row * NKEYS + col] = acc[mi][nj][r];
      }
}

// ---------------- topk: 16 tokens x 1 head per block ----------------
__global__ __launch_bounds__(256) void topk_kernel(
    const float* __restrict__ S,
    int* __restrict__ out_idx,
    float* __restrict__ out_prob)
{
  const int g = blockIdx.x;
  const int h = blockIdx.y;
  const int t = threadIdx.x;
  const int tok0 = g * 16;

  __shared__ float    sims  [16][2][128];
  __shared__ unsigned packed[16][2][128];
  __shared__ unsigned cmax  [16][2][8];
  __shared__ int      cnt   [16][2];
  __shared__ unsigned char surv[16][2][128];
  __shared__ float    stv   [16][2][8];
  __shared__ unsigned char sti[16][2][8];
  __shared__ unsigned cnd   [16][64];

  const int ltok = t >> 4, j0 = (t & 15) * 8;
  unsigned pk[2][8];
#pragma unroll
  for (int p = 0; p < 2; ++p) {
    const float* src = S + (((size_t)(p * 4 + h) * NTOK) + tok0 + ltok) * NKEYS + j0;
    const float4 a = ((const float4*)src)[0];
    const float4 b = ((const float4*)src)[1];
    float v[8] = {a.x, a.y, a.z, a.w, b.x, b.y, b.z, b.w};
#pragma unroll
    for (int e = 0; e < 8; ++e) {
      const unsigned u = (sortable(v[e]) & 0xFFFFFF80u) | (unsigned)(127 - (j0 + e));
      sims  [ltok][p][j0 + e] = v[e];
      packed[ltok][p][j0 + e] = u;
      pk[p][e] = u;
    }
  }
  if (t < 32) cnt[t >> 1][t & 1] = 0;
  __syncthreads();

  {
    const int ctok = t >> 4, cp = (t >> 3) & 1, c = t & 7;
    const uint4* q = (const uint4*)&packed[ctok][cp][c * 16];
    unsigned m = 0;
#pragma unroll
    for (int r = 0; r < 4; ++r) {
      const uint4 u = q[r];
      m = max(m, max(max(u.x, u.y), max(u.z, u.w)));
    }
    cmax[ctok][cp][c] = m;
  }
  __syncthreads();

#pragma unroll
  for (int p = 0; p < 2; ++p) {
    const uint4* cm = (const uint4*)&cmax[ltok][p][0];
    const uint4 ca = cm[0], cb = cm[1];
    const unsigned t0 = min(min(min(ca.x, ca.y), min(ca.z, ca.w)),
                            min(min(cb.x, cb.y), min(cb.z, cb.w)));
#pragma unroll
    for (int e = 0; e < 8; ++e) {
      if (pk[p][e] >= t0) {
        const int s = atomicAdd(&cnt[ltok][p], 1);
        surv[ltok][p][s] = (unsigned char)(j0 + e);
      }
    }
  }
  __syncthreads();

  {
    const int gid = t >> 3, lane8 = t & 7;
    const int stok = gid >> 1, sp = gid & 1;
    const int n = cnt[stok][sp];
    const uint4* row = (const uint4*)&packed[stok][sp][0];
    for (int s = lane8; s < n; s += 8) {
      const int j = surv[stok][sp][s];
      const unsigned mypk = packed[stok][sp][j];
      int rk = 0;
#pragma unroll 8
      for (int q4 = 0; q4 < 32; ++q4) {
        const uint4 u = row[q4];
        rk += (u.x > mypk) + (u.y > mypk) + (u.z > mypk) + (u.w > mypk);
      }
      if (rk < TOPK) {
        stv[stok][sp][rk] = sims[stok][sp][j];
        sti[stok][sp][rk] = (unsigned char)j;
      }
    }
  }
  __syncthreads();

  const int w = t >> 6, l = t & 63;
  for (int round = 0; round < 4; ++round) {
    const int tok = w * 4 + round;
    const int ci = l >> 3, cj = l & 7;
    const float cv = stv[tok][0][ci] + stv[tok][1][cj];
    const unsigned cpk = (sortable(cv) & 0xFFFFFFC0u) | (unsigned)(63 - l);
    cnd[tok][l] = cpk;
    __syncthreads();
    int rk = 0;
    const uint4* row = (const uint4*)&cnd[tok][0];
#pragma unroll
    for (int q4 = 0; q4 < 16; ++q4) {
      const uint4 u = row[q4];
      rk += (u.x > cpk) + (u.y > cpk) + (u.z > cpk) + (u.w > cpk);
    }
    float mx = cv;
#pragma unroll
    for (int off = 32; off; off >>= 1) mx = fmaxf(mx, __shfl_xor(mx, off));
    const float e = (rk < TOPK) ? __expf(cv - mx) : 0.f;
    float sum = e;
#pragma unroll
    for (int off = 32; off; off >>= 1) sum += __shfl_xor(sum, off);
    if (rk < TOPK) {
      const int o = ((tok0 + tok) * HEADS + h) * TOPK + rk;
      out_idx [o] = (int)sti[tok][0][ci] * NKEYS + (int)sti[tok][1][cj];
      out_prob[o] = e / sum;
    }
  }
}

// ---------------- expert mixture (bf16 embeds): 4 waves x 8 experts ----------------
__global__ __launch_bounds__(256) void expert_kernel(
    const float* __restrict__ hs,
    const __bf16* __restrict__ down_e,
    const __bf16* __restrict__ up_e,
    const int* __restrict__ idx,
    const float* __restrict__ prob,
    float* __restrict__ out)
{
  const int token = blockIdx.x;
  const int t = threadIdx.x, w = t >> 6, l = t & 63;
  __shared__ float4 sred[4][256];

  const float4* hrow = (const float4*)(hs + (size_t)token * HID);
  const float4 h0 = hrow[2 * l], h1 = hrow[2 * l + 1];
  const float4 h2 = hrow[128 + 2 * l], h3 = hrow[128 + 2 * l + 1];
  float4 a0 = {0,0,0,0}, a1 = {0,0,0,0}, a2 = {0,0,0,0}, a3 = {0,0,0,0};

  const int*   tidx  = idx  + token * 32 + w * 8;
  const float* tprob = prob + token * 32 + w * 8;
#pragma unroll 2
  for (int e = 0; e < 8; ++e) {
    const int   ex = tidx[e];
    const float p  = tprob[e];
    const uint4* dr = (const uint4*)(down_e + (size_t)ex * HID);
    const uint4 dA = dr[l], dB = dr[64 + l];
    float part = h0.x * bfl(dA.x) + h0.y * bfh(dA.x) + h0.z * bfl(dA.y) + h0.w * bfh(dA.y)
               + h1.x * bfl(dA.z) + h1.y * bfh(dA.z) + h1.z * bfl(dA.w) + h1.w * bfh(dA.w)
               + h2.x * bfl(dB.x) + h2.y * bfh(dB.x) + h2.z * bfl(dB.y) + h2.w * bfh(dB.y)
               + h3.x * bfl(dB.z) + h3.y * bfh(dB.z) + h3.z * bfl(dB.w) + h3.w * bfh(dB.w);
#pragma unroll
    for (int off = 32; off; off >>= 1) part += __shfl_xor(part, off);
    const float wgt = siluf(part) * p;
    const uint4* ur = (const uint4*)(up_e + (size_t)ex * HID);
    const uint4 uA = ur[l], uB = ur[64 + l];
    a0.x += wgt * bfl(uA.x); a0.y += wgt * bfh(uA.x); a0.z += wgt * bfl(uA.y); a0.w += wgt * bfh(uA.y);
    a1.x += wgt * bfl(uA.z); a1.y += wgt * bfh(uA.z); a1.z += wgt * bfl(uA.w); a1.w += wgt * bfh(uA.w);
    a2.x += wgt * bfl(uB.x); a2.y += wgt * bfh(uB.x); a2.z += wgt * bfl(uB.y); a2.w += wgt * bfh(uB.y);
    a3.x += wgt * bfl(uB.z); a3.y += wgt * bfh(uB.z); a3.z += wgt * bfl(uB.w); a3.w += wgt * bfh(uB.w);
  }
  sred[w][2 * l] = a0; sred[w][2 * l + 1] = a1;
  sred[w][128 + 2 * l] = a2; sred[w][128 + 2 * l + 1] = a3;
  __syncthreads();

  const float4 r0 = sred[0][t], r1 = sred[1][t], r2 = sred[2][t], r3 = sred[3][t];
  float4* o = (float4*)(out + (size_t)token * HID);
  float4 cur = o[t];
  cur.x += r0.x + r1.x + r2.x + r3.x;
  cur.y += r0.y + r1.y + r2.y + r3.y;
  cur.z += r0.z + r1.z + r2.z + r3.z;
  cur.w += r0.w + r1.w + r2.w + r3.w;
  o[t] = cur;
}

extern "C" void kernel_launch(void* const* d_in, const int* in_sizes, int n_in,
                              void* d_out, int out_size, void* d_ws, size_t ws_size,
                              hipStream_t stream)
{
  const float* hs   = (const float*)d_in[0];
  const float* Wq   = (const float*)d_in[1];
  const float* keys = (const float*)d_in[2];
  const float* dwe  = (const float*)d_in[3];
  const float* upe  = (const float*)d_in[4];
  const float* Wg   = (const float*)d_in[5];
  const float* Wu   = (const float*)d_in[6];
  const float* Wd   = (const float*)d_in[7];
  float* out = (float*)d_out;

  __bf16* qbf     = (__bf16*)d_ws;                        // 4096*512 bf16 (4MB)
  __bf16* kbf     = qbf + (size_t)NTOK * QDIM;            // 8*128*64 bf16 (128KB)
  int*    idxb    = (int*)(kbf + 8 * NKEYS * 64);
  float*  probb   = (float*)(idxb + NTOK * HEADS * TOPK);
  __bf16* hs_bf   = (__bf16*)(probb + NTOK * HEADS * TOPK);
  __bf16* wq_bf   = hs_bf + (size_t)NTOK * HID;
  __bf16* wgu_bf  = wq_bf + (size_t)QDIM * HID;           // 8192*1024 bf16 (16MB)
  __bf16* wd_bf   = wgu_bf + (size_t)2 * INTERDIM * HID;
  __bf16* interbf = wd_bf + (size_t)HID * INTERDIM;       // 4096*4096 bf16 (32MB)
  float*  simsb   = (float*)interbf;                      // overlay, dead before gateup
  __bf16* dwe_bf  = interbf;                              // overlay, after down-GEMM
  __bf16* upe_bf  = hs_bf;                                // overlay (hs..wd span 33MB)

  cast_bf16_kernel<<<4096, 256, 0, stream>>>(hs, hs_bf, NTOK * HID / 4);
  cast_bf16_kernel<<<512,  256, 0, stream>>>(Wq, wq_bf, QDIM * HID / 4);
  cast_wgu_kernel<<<2048, 256, 0, stream>>>(Wg, Wu, wgu_bf);
  cast_bf16_kernel<<<4096, 256, 0, stream>>>(Wd, wd_bf, HID * INTERDIM / 4);
  cast_keys_kernel<<<256, 256, 0, stream>>>(keys, kbf);

  // q = hs @ Wq^T  (bf16 out)
  gemm_mfma<true><<<dim3(QDIM / 128, NTOK / 128), 512, 0, stream>>>(
      hs_bf, wq_bf, qbf, NTOK, QDIM, HID);

  // sims + topk
  sims_gemm<<<dim3(NTOK / 128, 8), 256, 0, stream>>>(qbf, kbf, simsb);
  topk_kernel<<<dim3(NTOK / 16, HEADS), 256, 0, stream>>>(simsb, idxb, probb);

  // inter = silu(hs @ Wg^T) * (hs @ Wu^T)  via concat-interleaved pipelined GEMM
  gemm_gateup<<<dim3(2 * INTERDIM / 256, NTOK / 256), 512, 0, stream>>>(
      hs_bf, wgu_bf, interbf, NTOK, 2 * INTERDIM, HID);

  // out = inter @ Wd^T  (f32 out)
  gemm_mfma<false><<<dim3(HID / 128, NTOK / 128), 512, 0, stream>>>(
      interbf, wd_bf, out, NTOK, HID, INTERDIM);

  // cast expert embeds into now-dead regions
  cast_bf16_kernel<<<4096, 256, 0, stream>>>(dwe, dwe_bf, 16384 * HID / 4);
  cast_bf16_kernel<<<4096, 256, 0, stream>>>(upe, upe_bf, 16384 * HID / 4);

  // out += expert mixture
  expert_kernel<<<NTOK, 256, 0, stream>>>(hs, dwe_bf, upe_bf, idxb, probb, out);
}

// Round 9
// 354.557 us; speedup vs baseline: 1.0400x; 1.0372x over previous
//
#include <hip/hip_runtime.h>

#define NTOK 4096
#define HID 1024
#define QDIM 512
#define HEADS 4
#define NKEYS 128
#define TOPK 8
#define INTERDIM 4096

typedef __bf16 bf16x8 __attribute__((ext_vector_type(8)));
typedef __bf16 bf16x4 __attribute__((ext_vector_type(4)));
typedef float f32x4 __attribute__((ext_vector_type(4)));

__device__ __forceinline__ float siluf(float x) { return x / (1.f + __expf(-x)); }
__device__ __forceinline__ unsigned sortable(float f) {
  unsigned u = __float_as_uint(f);
  return (u & 0x80000000u) ? ~u : (u | 0x80000000u);
}
__device__ __forceinline__ float bfl(unsigned u) { return __uint_as_float(u << 16); }
__device__ __forceinline__ float bfh(unsigned u) { return __uint_as_float(u & 0xFFFF0000u); }

#define GLD_LDS16(g, l)                                                                   \
  __builtin_amdgcn_global_load_lds(                                                      \
      (const __attribute__((address_space(1))) unsigned int*)(g),                        \
      (__attribute__((address_space(3))) unsigned int*)(l), 16, 0, 0)

// ---------------- fp32 -> bf16 cast ----------------
__global__ __launch_bounds__(256) void cast_bf16_kernel(const float* __restrict__ in,
                                                        __bf16* __restrict__ out, int n4)
{
  const int stride = gridDim.x * blockDim.x;
  for (int i = blockIdx.x * blockDim.x + threadIdx.x; i < n4; i += stride) {
    const float4 v = ((const float4*)in)[i];
    bf16x4 o;
    o[0] = (__bf16)v.x; o[1] = (__bf16)v.y; o[2] = (__bf16)v.z; o[3] = (__bf16)v.w;
    ((bf16x4*)out)[i] = o;
  }
}

// keys [h][k][p][n] f32 -> kbf [(p*4+h)][k][n] bf16
__global__ __launch_bounds__(256) void cast_keys_kernel(const float* __restrict__ keys,
                                                        __bf16* __restrict__ kbf)
{
  const int i = blockIdx.x * 256 + threadIdx.x;
  const int n = i & 63, p = (i >> 6) & 1, k = (i >> 7) & 127, h = (i >> 14) & 3;
  kbf[(((size_t)(p * 4 + h) * NKEYS) + k) * 64 + n] = (__bf16)keys[i];
}

// ---------------- bf16 MFMA GEMM: C[M,N] = A[M,K] @ B[N,K]^T ----------------
// Round-6 proven structure: 512 threads / 8 waves (2Mx4N), tile 128x128, BK=32,
// wave tile 64x32 (4x2 frags of 16x16x32), global_load_lds width-16, 2 barriers/K-step.
// NEW: 2D-region XCD swizzle for L2 locality. Grid is split into 8 BWxBH block
// rectangles (one per XCD, assuming dispatch round-robins bid%8 -> XCD; perf-only).
// Within a region, bx walks fastest so the B panel set (<= L2) is reused across BH A-rows.
template<bool DUAL, bool OUT_BF16>
__global__ __launch_bounds__(512) void gemm_mfma(
    const __bf16* __restrict__ A, const __bf16* __restrict__ B0,
    const __bf16* __restrict__ B1, void* __restrict__ Cv,
    int M, int N, int K, int BW, int BH, int NRX)
{
  __shared__ __attribute__((aligned(16))) __bf16 As [128 * 32];
  __shared__ __attribute__((aligned(16))) __bf16 Bs0[128 * 32];
  __shared__ __attribute__((aligned(16))) __bf16 Bs1[DUAL ? 128 * 32 : 8];

  // region swizzle: xcd = bid&7 owns a BWxBH rectangle at (rx, ry)
  const int bid = blockIdx.y * gridDim.x + blockIdx.x;
  const int xcd = bid & 7, idx = bid >> 3;
  const int rx = (xcd % NRX) * BW;
  const int ry = (xcd / NRX) * BH;
  const int bx = rx + idx % BW;
  const int by = ry + idx / BW;

  const int tid  = threadIdx.x;
  const int wave = tid >> 6;
  const int lane = tid & 63;
  const int m0 = by * 128;
  const int n0 = bx * 128;
  const int wr = wave >> 2, wc = wave & 3;       // 2 x 4 wave grid
  const int lhi = lane >> 4, llo = lane & 15;

  f32x4 acc0[4][2] = {};
  f32x4 acc1[4][2] = {};

  const int r0 = tid >> 2, col0 = (tid & 3) * 8;
  __bf16* ldsA  = &As [(size_t)wave * 512];
  __bf16* ldsB0 = &Bs0[(size_t)wave * 512];
  __bf16* ldsB1 = &Bs1[(size_t)wave * 512];

  for (int k0 = 0; k0 < K; k0 += 32) {
    GLD_LDS16(A  + (size_t)(m0 + r0) * K + k0 + col0, ldsA);
    GLD_LDS16(B0 + (size_t)(n0 + r0) * K + k0 + col0, ldsB0);
    if constexpr (DUAL)
      GLD_LDS16(B1 + (size_t)(n0 + r0) * K + k0 + col0, ldsB1);
    __syncthreads();

    bf16x8 afr[4], bfr0[2], bfr1[2];
#pragma unroll
    for (int mi = 0; mi < 4; ++mi)
      afr[mi] = *(const bf16x8*)&As[(wr * 64 + mi * 16 + llo) * 32 + lhi * 8];
#pragma unroll
    for (int nj = 0; nj < 2; ++nj)
      bfr0[nj] = *(const bf16x8*)&Bs0[(wc * 32 + nj * 16 + llo) * 32 + lhi * 8];
    if constexpr (DUAL) {
#pragma unroll
      for (int nj = 0; nj < 2; ++nj)
        bfr1[nj] = *(const bf16x8*)&Bs1[(wc * 32 + nj * 16 + llo) * 32 + lhi * 8];
    }
#pragma unroll
    for (int mi = 0; mi < 4; ++mi)
#pragma unroll
      for (int nj = 0; nj < 2; ++nj) {
        acc0[mi][nj] = __builtin_amdgcn_mfma_f32_16x16x32_bf16(afr[mi], bfr0[nj], acc0[mi][nj], 0, 0, 0);
        if constexpr (DUAL)
          acc1[mi][nj] = __builtin_amdgcn_mfma_f32_16x16x32_bf16(afr[mi], bfr1[nj], acc1[mi][nj], 0, 0, 0);
      }
    __syncthreads();
  }

#pragma unroll
  for (int mi = 0; mi < 4; ++mi)
#pragma unroll
    for (int nj = 0; nj < 2; ++nj)
#pragma unroll
      for (int r = 0; r < 4; ++r) {
        const int row = m0 + wr * 64 + mi * 16 + lhi * 4 + r;
        const int col = n0 + wc * 32 + nj * 16 + llo;
        float v = acc0[mi][nj][r];
        if constexpr (DUAL) v = siluf(v) * acc1[mi][nj][r];
        if constexpr (OUT_BF16) ((__bf16*)Cv)[(size_t)row * N + col] = (__bf16)v;
        else                    ((float*) Cv)[(size_t)row * N + col] = v;
      }
}

// ---------------- batched sims GEMM ----------------
__global__ __launch_bounds__(256) void sims_gemm(
    const __bf16* __restrict__ Qbf,  // [4096][512]
    const __bf16* __restrict__ Kbf,  // [8][128][64]
    float* __restrict__ S)           // [8][4096][128]
{
  __shared__ __attribute__((aligned(16))) __bf16 As[128 * 32];
  __shared__ __attribute__((aligned(16))) __bf16 Bs[128 * 32];

  const int z = blockIdx.y;
  const int p = z >> 2, h = z & 3;
  const __bf16* A = Qbf + p * 256 + h * 64;
  const __bf16* B = Kbf + (size_t)z * NKEYS * 64;
  float* C = S + (size_t)z * NTOK * NKEYS;

  const int tid  = threadIdx.x;
  const int wave = tid >> 6;
  const int lane = tid & 63;
  const int m0 = blockIdx.x * 128;
  const int wr = wave >> 1, wc = wave & 1;
  const int lhi = lane >> 4, llo = lane & 15;

  f32x4 acc[4][4] = {};

  const int c0 = tid, c1 = 256 + tid;
  const int r0 = c0 >> 2, col0 = (c0 & 3) * 8;
  const int r1 = c1 >> 2, col1 = (c1 & 3) * 8;
  __bf16* ldsA0 = &As[(wave * 64) * 8];
  __bf16* ldsA1 = &As[(256 + wave * 64) * 8];
  __bf16* ldsB0 = &Bs[(wave * 64) * 8];
  __bf16* ldsB1 = &Bs[(256 + wave * 64) * 8];

  for (int k0 = 0; k0 < 64; k0 += 32) {
    GLD_LDS16(A + (size_t)(m0 + r0) * 512 + k0 + col0, ldsA0);
    GLD_LDS16(A + (size_t)(m0 + r1) * 512 + k0 + col1, ldsA1);
    GLD_LDS16(B + (size_t)r0 * 64 + k0 + col0, ldsB0);
    GLD_LDS16(B + (size_t)r1 * 64 + k0 + col1, ldsB1);
    __syncthreads();

    bf16x8 afr[4], bfr[4];
#pragma unroll
    for (int mi = 0; mi < 4; ++mi)
      afr[mi] = *(const bf16x8*)&As[(wr * 64 + mi * 16 + llo) * 32 + lhi * 8];
#pragma unroll
    for (int nj = 0; nj < 4; ++nj)
      bfr[nj] = *(const bf16x8*)&Bs[(wc * 64 + nj * 16 + llo) * 32 + lhi * 8];
#pragma unroll
    for (int mi = 0; mi < 4; ++mi)
#pragma unroll
      for (int nj = 0; nj < 4; ++nj)
        acc[mi][nj] = __builtin_amdgcn_mfma_f32_16x16x32_bf16(afr[mi], bfr[nj], acc[mi][nj], 0, 0, 0);
    __syncthreads();
  }

#pragma unroll
  for (int mi = 0; mi < 4; ++mi)
#pragma unroll
    for (int nj = 0; nj < 4; ++nj)
#pragma unroll
      for (int r = 0; r < 4; ++r) {
        const int row = m0 + wr * 64 + mi * 16 + lhi * 4 + r;
        const int col = wc * 64 + nj * 16 + llo;
        C[(size_t)row * NKEYS + col] = acc[mi][nj][r];
      }
}

// ---------------- topk: 16 tokens x 1 head per block ----------------
__global__ __launch_bounds__(256) void topk_kernel(
    const float* __restrict__ S,
    int* __restrict__ out_idx,
    float* __restrict__ out_prob)
{
  const int g = blockIdx.x;
  const int h = blockIdx.y;
  const int t = threadIdx.x;
  const int tok0 = g * 16;

  __shared__ float    sims  [16][2][128];
  __shared__ unsigned packed[16][2][128];
  __shared__ unsigned cmax  [16][2][8];
  __shared__ int      cnt   [16][2];
  __shared__ unsigned char surv[16][2][128];
  __shared__ float    stv   [16][2][8];
  __shared__ unsigned char sti[16][2][8];
  __shared__ unsigned cnd   [16][64];

  const int ltok = t >> 4, j0 = (t & 15) * 8;
  unsigned pk[2][8];
#pragma unroll
  for (int p = 0; p < 2; ++p) {
    const float* src = S + (((size_t)(p * 4 + h) * NTOK) + tok0 + ltok) * NKEYS + j0;
    const float4 a = ((const float4*)src)[0];
    const float4 b = ((const float4*)src)[1];
    float v[8] = {a.x, a.y, a.z, a.w, b.x, b.y, b.z, b.w};
#pragma unroll
    for (int e = 0; e < 8; ++e) {
      const unsigned u = (sortable(v[e]) & 0xFFFFFF80u) | (unsigned)(127 - (j0 + e));
      sims  [ltok][p][j0 + e] = v[e];
      packed[ltok][p][j0 + e] = u;
      pk[p][e] = u;
    }
  }
  if (t < 32) cnt[t >> 1][t & 1] = 0;
  __syncthreads();

  {
    const int ctok = t >> 4, cp = (t >> 3) & 1, c = t & 7;
    const uint4* q = (const uint4*)&packed[ctok][cp][c * 16];
    unsigned m = 0;
#pragma unroll
    for (int r = 0; r < 4; ++r) {
      const uint4 u = q[r];
      m = max(m, max(max(u.x, u.y), max(u.z, u.w)));
    }
    cmax[ctok][cp][c] = m;
  }
  __syncthreads();

#pragma unroll
  for (int p = 0; p < 2; ++p) {
    const uint4* cm = (const uint4*)&cmax[ltok][p][0];
    const uint4 ca = cm[0], cb = cm[1];
    const unsigned t0 = min(min(min(ca.x, ca.y), min(ca.z, ca.w)),
                            min(min(cb.x, cb.y), min(cb.z, cb.w)));
#pragma unroll
    for (int e = 0; e < 8; ++e) {
      if (pk[p][e] >= t0) {
        const int s = atomicAdd(&cnt[ltok][p], 1);
        surv[ltok][p][s] = (unsigned char)(j0 + e);
      }
    }
  }
  __syncthreads();

  {
    const int gid = t >> 3, lane8 = t & 7;
    const int stok = gid >> 1, sp = gid & 1;
    const int n = cnt[stok][sp];
    const uint4* row = (const uint4*)&packed[stok][sp][0];
    for (int s = lane8; s < n; s += 8) {
      const int j = surv[stok][sp][s];
      const unsigned mypk = packed[stok][sp][j];
      int rk = 0;
#pragma unroll 8
      for (int q4 = 0; q4 < 32; ++q4) {
        const uint4 u = row[q4];
        rk += (u.x > mypk) + (u.y > mypk) + (u.z > mypk) + (u.w > mypk);
      }
      if (rk < TOPK) {
        stv[stok][sp][rk] = sims[stok][sp][j];
        sti[stok][sp][rk] = (unsigned char)j;
      }
    }
  }
  __syncthreads();

  const int w = t >> 6, l = t & 63;
  for (int round = 0; round < 4; ++round) {
    const int tok = w * 4 + round;
    const int ci = l >> 3, cj = l & 7;
    const float cv = stv[tok][0][ci] + stv[tok][1][cj];
    const unsigned cpk = (sortable(cv) & 0xFFFFFFC0u) | (unsigned)(63 - l);
    cnd[tok][l] = cpk;
    __syncthreads();
    int rk = 0;
    const uint4* row = (const uint4*)&cnd[tok][0];
#pragma unroll
    for (int q4 = 0; q4 < 16; ++q4) {
      const uint4 u = row[q4];
      rk += (u.x > cpk) + (u.y > cpk) + (u.z > cpk) + (u.w > cpk);
    }
    float mx = cv;
#pragma unroll
    for (int off = 32; off; off >>= 1) mx = fmaxf(mx, __shfl_xor(mx, off));
    const float e = (rk < TOPK) ? __expf(cv - mx) : 0.f;
    float sum = e;
#pragma unroll
    for (int off = 32; off; off >>= 1) sum += __shfl_xor(sum, off);
    if (rk < TOPK) {
      const int o = ((tok0 + tok) * HEADS + h) * TOPK + rk;
      out_idx [o] = (int)sti[tok][0][ci] * NKEYS + (int)sti[tok][1][cj];
      out_prob[o] = e / sum;
    }
  }
}

// ---------------- expert mixture (bf16 embeds): 4 waves x 8 experts ----------------
__global__ __launch_bounds__(256) void expert_kernel(
    const float* __restrict__ hs,
    const __bf16* __restrict__ down_e,
    const __bf16* __restrict__ up_e,
    const int* __restrict__ idx,
    const float* __restrict__ prob,
    float* __restrict__ out)
{
  const int token = blockIdx.x;
  const int t = threadIdx.x, w = t >> 6, l = t & 63;
  __shared__ float4 sred[4][256];

  const float4* hrow = (const float4*)(hs + (size_t)token * HID);
  const float4 h0 = hrow[2 * l], h1 = hrow[2 * l + 1];
  const float4 h2 = hrow[128 + 2 * l], h3 = hrow[128 + 2 * l + 1];
  float4 a0 = {0,0,0,0}, a1 = {0,0,0,0}, a2 = {0,0,0,0}, a3 = {0,0,0,0};

  const int*   tidx  = idx  + token * 32 + w * 8;
  const float* tprob = prob + token * 32 + w * 8;
#pragma unroll 2
  for (int e = 0; e < 8; ++e) {
    const int   ex = tidx[e];
    const float p  = tprob[e];
    const uint4* dr = (const uint4*)(down_e + (size_t)ex * HID);
    const uint4 dA = dr[l], dB = dr[64 + l];
    float part = h0.x * bfl(dA.x) + h0.y * bfh(dA.x) + h0.z * bfl(dA.y) + h0.w * bfh(dA.y)
               + h1.x * bfl(dA.z) + h1.y * bfh(dA.z) + h1.z * bfl(dA.w) + h1.w * bfh(dA.w)
               + h2.x * bfl(dB.x) + h2.y * bfh(dB.x) + h2.z * bfl(dB.y) + h2.w * bfh(dB.y)
               + h3.x * bfl(dB.z) + h3.y * bfh(dB.z) + h3.z * bfl(dB.w) + h3.w * bfh(dB.w);
#pragma unroll
    for (int off = 32; off; off >>= 1) part += __shfl_xor(part, off);
    const float wgt = siluf(part) * p;
    const uint4* ur = (const uint4*)(up_e + (size_t)ex * HID);
    const uint4 uA = ur[l], uB = ur[64 + l];
    a0.x += wgt * bfl(uA.x); a0.y += wgt * bfh(uA.x); a0.z += wgt * bfl(uA.y); a0.w += wgt * bfh(uA.y);
    a1.x += wgt * bfl(uA.z); a1.y += wgt * bfh(uA.z); a1.z += wgt * bfl(uA.w); a1.w += wgt * bfh(uA.w);
    a2.x += wgt * bfl(uB.x); a2.y += wgt * bfh(uB.x); a2.z += wgt * bfl(uB.y); a2.w += wgt * bfh(uB.y);
    a3.x += wgt * bfl(uB.z); a3.y += wgt * bfh(uB.z); a3.z += wgt * bfl(uB.w); a3.w += wgt * bfh(uB.w);
  }
  sred[w][2 * l] = a0; sred[w][2 * l + 1] = a1;
  sred[w][128 + 2 * l] = a2; sred[w][128 + 2 * l + 1] = a3;
  __syncthreads();

  const float4 r0 = sred[0][t], r1 = sred[1][t], r2 = sred[2][t], r3 = sred[3][t];
  float4* o = (float4*)(out + (size_t)token * HID);
  float4 cur = o[t];
  cur.x += r0.x + r1.x + r2.x + r3.x;
  cur.y += r0.y + r1.y + r2.y + r3.y;
  cur.z += r0.z + r1.z + r2.z + r3.z;
  cur.w += r0.w + r1.w + r2.w + r3.w;
  o[t] = cur;
}

extern "C" void kernel_launch(void* const* d_in, const int* in_sizes, int n_in,
                              void* d_out, int out_size, void* d_ws, size_t ws_size,
                              hipStream_t stream)
{
  const float* hs   = (const float*)d_in[0];
  const float* Wq   = (const float*)d_in[1];
  const float* keys = (const float*)d_in[2];
  const float* dwe  = (const float*)d_in[3];
  const float* upe  = (const float*)d_in[4];
  const float* Wg   = (const float*)d_in[5];
  const float* Wu   = (const float*)d_in[6];
  const float* Wd   = (const float*)d_in[7];
  float* out = (float*)d_out;

  __bf16* qbf     = (__bf16*)d_ws;                        // 4096*512 bf16 (4MB)
  __bf16* kbf     = qbf + (size_t)NTOK * QDIM;            // 8*128*64 bf16 (128KB)
  int*    idxb    = (int*)(kbf + 8 * NKEYS * 64);
  float*  probb   = (float*)(idxb + NTOK * HEADS * TOPK);
  __bf16* hs_bf   = (__bf16*)(probb + NTOK * HEADS * TOPK);
  __bf16* wq_bf   = hs_bf + (size_t)NTOK * HID;
  __bf16* wg_bf   = wq_bf + (size_t)QDIM * HID;
  __bf16* wu_bf   = wg_bf + (size_t)INTERDIM * HID;
  __bf16* wd_bf   = wu_bf + (size_t)INTERDIM * HID;
  __bf16* interbf = wd_bf + (size_t)HID * INTERDIM;       // 4096*4096 bf16 (32MB)
  float*  simsb   = (float*)interbf;                      // overlay, dead before dual-gemm
  __bf16* dwe_bf  = interbf;                              // overlay, after down-GEMM
  __bf16* upe_bf  = hs_bf;                                // overlay (hs..wd span 33MB)

  cast_bf16_kernel<<<4096, 256, 0, stream>>>(hs, hs_bf, NTOK * HID / 4);
  cast_bf16_kernel<<<512,  256, 0, stream>>>(Wq, wq_bf, QDIM * HID / 4);
  cast_bf16_kernel<<<4096, 256, 0, stream>>>(Wg, wg_bf, INTERDIM * HID / 4);
  cast_bf16_kernel<<<4096, 256, 0, stream>>>(Wu, wu_bf, INTERDIM * HID / 4);
  cast_bf16_kernel<<<4096, 256, 0, stream>>>(Wd, wd_bf, HID * INTERDIM / 4);
  cast_keys_kernel<<<256, 256, 0, stream>>>(keys, kbf);

  // q = hs @ Wq^T  (bf16 out). grid (4,32): regions 4x4, NRX=1
  gemm_mfma<false, true><<<dim3(QDIM / 128, NTOK / 128), 512, 0, stream>>>(
      hs_bf, wq_bf, nullptr, qbf, NTOK, QDIM, HID, 4, 4, 1);

  // sims + topk
  sims_gemm<<<dim3(NTOK / 128, 8), 256, 0, stream>>>(qbf, kbf, simsb);
  topk_kernel<<<dim3(NTOK / 16, HEADS), 256, 0, stream>>>(simsb, idxb, probb);

  // inter = silu(hs @ Wg^T) * (hs @ Wu^T)  (bf16 out). grid (32,32): regions 8x16, NRX=4
  gemm_mfma<true, true><<<dim3(INTERDIM / 128, NTOK / 128), 512, 0, stream>>>(
      hs_bf, wg_bf, wu_bf, interbf, NTOK, INTERDIM, HID, 8, 16, 4);

  // out = inter @ Wd^T  (f32 out). grid (8,32): regions 8x4, NRX=1
  gemm_mfma<false, false><<<dim3(HID / 128, NTOK / 128), 512, 0, stream>>>(
      interbf, wd_bf, nullptr, out, NTOK, HID, INTERDIM, 8, 4, 1);

  // cast expert embeds into now-dead regions
  cast_bf16_kernel<<<4096, 256, 0, stream>>>(dwe, dwe_bf, 16384 * HID / 4);
  cast_bf16_kernel<<<4096, 256, 0, stream>>>(upe, upe_bf, 16384 * HID / 4);

  // out += expert mixture
  expert_kernel<<<NTOK, 256, 0, stream>>>(hs, dwe_bf, upe_bf, idxb, probb, out);
}